// Round 20
// baseline (241.120 us; speedup 1.0000x reference)
//
#include <hip/hip_runtime.h>
#include <hip/hip_bf16.h>

using f32x4  = __attribute__((ext_vector_type(4))) float;
using bf16x8 = __attribute__((ext_vector_type(8))) short;
typedef unsigned int u32;
typedef unsigned short u16;

#define KD 128
#define NBINS 512
#define CHUNKP 2048     // place chunk (LDS-resident); 8 entries/thread
#define EPT 8
#define CAPB 8192
#define MAXB 10240
#define NSEGMAX 768
#define GSTR 16         // gcur padding stride (64B per bin)

__device__ inline float bf2f(short s){
  return __uint_as_float(((u32)(u16)s) << 16);
}

struct BinParams {
  long Cb[4]; int base[4]; double dr[4]; double dbin; int nseg;
};

__device__ inline int bin_of(int seg, const BinParams& bp){
  int r = (seg >= bp.base[1]) + (seg >= bp.base[2]) + (seg >= bp.base[3]);
  long ep = bp.Cb[r] + (long)((double)(seg - bp.base[r]) * bp.dr[r]);
  int b = (int)((double)ep * bp.dbin);
  return (b > NBINS - 1) ? (NBINS - 1) : b;
}

// ---------------- pb512: bin -> first seg ----------------
__global__ void k_pb512(BinParams bp, int* __restrict__ pb){
  int t = blockIdx.x * blockDim.x + threadIdx.x;
  if (t > NBINS) return;
  if (t == 0){ pb[0] = 0; return; }
  if (t == NBINS){ pb[NBINS] = bp.nseg; return; }
  int lo = 0, hi = bp.nseg;
  while (lo < hi){
    int mid = (lo + hi) >> 1;
    if (bin_of(mid, bp) >= t) hi = mid; else lo = mid + 1;
  }
  pb[t] = lo;
}

// ---------------- weight convert ----------------
__global__ __launch_bounds__(256) void k_cvt_w(const float* __restrict__ w0,
                                               const float* __restrict__ w1,
                                               const float* __restrict__ w2,
                                               const float* __restrict__ w3,
                                               short* __restrict__ out){
  int i = blockIdx.x * 256 + threadIdx.x;
  const float* src = (i < 16384) ? w0 : (i < 32768) ? w1 : (i < 49152) ? w2 : w3;
  float v = src[i & 16383];
  __hip_bfloat16 b = __float2bfloat16(v);
  out[i] = __builtin_bit_cast(short, b);
}

// ---------------- shared-memory overlay structs (256-thread fused kernel) ----------------
struct PlaceSh {
  u32 sorted[CHUNKP];   // 8KB
  u16 sbid[CHUNKP];     // 4KB
  int cnt[NBINS];
  int lbase[NBINS];
  int lpos[NBINS];
  int pbL[NBINS];       // 8KB
  int sc[256];          // 1KB
};                      // ~21.3KB
struct GemmSh { short zst[4][16][136]; };   // 17KB

// ---------------- GEMM z = h @ W^T (+ ews = exp(z . attn)) ----------------
struct GJob { const float* A1; const float* attn; __hip_bfloat16* Z; float* ews;
              int zbase, nrows, blk0, wboff; };

__device__ void gemm_body(GemmSh* g,
                          const float* __restrict__ A0, int nA,
                          const float* __restrict__ A1,
                          const short* __restrict__ Wb, const float* __restrict__ attn,
                          __hip_bfloat16* __restrict__ Z, float* __restrict__ ews,
                          int zbase, int nrows, int blk)
{
  const int wave = threadIdx.x >> 6, lane = threadIdx.x & 63;
  const int lr = lane & 15, lk = lane >> 4;
  const int row0 = blk * 64 + wave * 16;

  bf16x8 afrag[4];
  {
    int r = row0 + lr;
    bool rv = (r < nrows);
    int node = zbase + r;
    const float* ap = A0;
    if (rv) ap = (node < nA) ? (A0 + (size_t)node * KD) : (A1 + (size_t)(node - nA) * KD);
#pragma unroll
    for (int t = 0; t < 4; ++t){
      float x[8];
      if (rv){
        float4 u0 = *(const float4*)(ap + t * 32 + lk * 8);
        float4 u1 = *(const float4*)(ap + t * 32 + lk * 8 + 4);
        x[0]=u0.x; x[1]=u0.y; x[2]=u0.z; x[3]=u0.w;
        x[4]=u1.x; x[5]=u1.y; x[6]=u1.z; x[7]=u1.w;
      } else {
#pragma unroll
        for (int j = 0; j < 8; ++j) x[j] = 0.f;
      }
      bf16x8 af;
#pragma unroll
      for (int j = 0; j < 8; ++j){
        __hip_bfloat16 b = __float2bfloat16(x[j]);
        af[j] = __builtin_bit_cast(short, b);
      }
      afrag[t] = af;
    }
  }

  f32x4 acc[8];
#pragma unroll
  for (int c = 0; c < 8; ++c){ acc[c][0]=0.f; acc[c][1]=0.f; acc[c][2]=0.f; acc[c][3]=0.f; }

#pragma unroll
  for (int c = 0; c < 8; ++c){
#pragma unroll
    for (int t = 0; t < 4; ++t){
      bf16x8 bf = *(const bf16x8*)(Wb + (c * 16 + lr) * KD + t * 32 + lk * 8);
      acc[c] = __builtin_amdgcn_mfma_f32_16x16x32_bf16(afrag[t], bf, acc[c], 0, 0, 0);
    }
  }

  float p[4] = {0.f, 0.f, 0.f, 0.f};
#pragma unroll
  for (int c = 0; c < 8; ++c){
    float av = attn[c * 16 + lr];
#pragma unroll
    for (int q = 0; q < 4; ++q){
      p[q] += acc[c][q] * av;
      g->zst[wave][lk * 4 + q][c * 16 + lr] =
          __builtin_bit_cast(short, __float2bfloat16(acc[c][q]));
    }
  }
#pragma unroll
  for (int q = 0; q < 4; ++q){
#pragma unroll
    for (int o = 1; o < 16; o <<= 1) p[q] += __shfl_xor(p[q], o, 64);
  }
  if (lr == 0){
#pragma unroll
    for (int q = 0; q < 4; ++q){
      int r = row0 + lk * 4 + q;
      if (r < nrows) ews[r] = __expf(p[q]);   // max-shift cancels in segment softmax
    }
  }
  __syncthreads();
#pragma unroll
  for (int pq = 0; pq < 4; ++pq){
    int row = pq * 4 + (lane >> 4);
    int col8 = (lane & 15) * 8;
    bf16x8 v = *(const bf16x8*)&g->zst[wave][row][col8];
    int r = row0 + row;
    if (r < nrows) *(bf16x8*)(Z + (size_t)r * KD + col8) = v;
  }
}

// ---------------- megaF: place blocks + gemm blocks (256 threads, LDS overlay) ----------------
struct MegaArgs {
  const int* d0; const int* s0; const int* d1; const int* s1;
  const int* d2; const int* s2; const int* d3; const int* s3;
  int nse, nek, rebase23, nplace;
  u32* buckets;
  int* gcur;              // padded: bin j at gcur[j*GSTR]
  const int* pb;
  BinParams bp;
  const float* A0; int nA;
  const short* Wb;
  GJob j[4];
};

__global__ __launch_bounds__(256) void k_megaF(MegaArgs a){
  __shared__ alignas(16) char shraw[sizeof(PlaceSh)];
  const int tid = threadIdx.x;
  const int b = blockIdx.x;
  if (b < a.nplace){
    PlaceSh& P = *reinterpret_cast<PlaceSh*>(shraw);
    for (int j = tid; j < NBINS; j += 256){ P.cnt[j] = 0; P.pbL[j] = a.pb[j]; }
    __syncthreads();
    const long total = 2L * a.nse + 2L * a.nek;
    long c0 = (long)b * CHUNKP;
    long c1 = c0 + CHUNKP; if (c1 > total) c1 = total;

    // pass A: load once, stage entries in registers, build local hist
    u32 re[EPT];
    int rbn[EPT];
#pragma unroll
    for (int it = 0; it < EPT; ++it){
      long i = c0 + (long)it * 256 + tid;
      rbn[it] = -1;
      if (i < c1){
        long k = i; const int* dp; const int* sp; int rb;
        if (k < a.nse){ dp = a.d0; sp = a.s0; rb = 0; }
        else if ((k -= a.nse) < a.nse){ dp = a.d1; sp = a.s1; rb = 0; }
        else if ((k -= a.nse) < a.nek){ dp = a.d2; sp = a.s2; rb = a.rebase23; }
        else { k -= a.nek; dp = a.d3; sp = a.s3; rb = a.rebase23; }
        int seg = dp[k] + rb;
        int bn = bin_of(seg, a.bp);
        re[it]  = ((u32)(seg - P.pbL[bn]) << 16) | (u32)sp[k];
        rbn[it] = bn;
        atomicAdd(&P.cnt[bn], 1);
      }
    }
    __syncthreads();
    // exclusive scan (512 bins, 256 threads, 2 rounds)
    int carry = 0;
    for (int cb = 0; cb < NBINS; cb += 256){
      int j = cb + tid;
      int v = P.cnt[j];
      P.sc[tid] = v; __syncthreads();
      for (int o = 1; o < 256; o <<= 1){
        int u = (tid >= o) ? P.sc[tid - o] : 0;
        __syncthreads();
        P.sc[tid] += u;
        __syncthreads();
      }
      P.lbase[j] = carry + P.sc[tid] - v;
      P.lpos[j]  = P.lbase[j];
      carry += P.sc[255];
      __syncthreads();
    }
    // reserve global runs (padded gcur); cnt[] becomes gbs[]
    for (int j = tid; j < NBINS; j += 256){
      int c = P.cnt[j];
      P.cnt[j] = c ? atomicAdd(&a.gcur[j * GSTR], c) : 0;
    }
    __syncthreads();
    // pass B: scatter from registers into LDS (sorted by bin)
#pragma unroll
    for (int it = 0; it < EPT; ++it){
      if (rbn[it] >= 0){
        int p = atomicAdd(&P.lpos[rbn[it]], 1);
        P.sorted[p] = re[it];
        P.sbid[p] = (u16)rbn[it];
      }
    }
    __syncthreads();
    // coalesced-run dump into per-bin buckets
    int n = (int)(c1 - c0);
    for (int i = tid; i < n; i += 256){
      int bn = P.sbid[i];
      int idx = P.cnt[bn] + (i - P.lbase[bn]);
      if (idx < CAPB)
        __builtin_nontemporal_store(P.sorted[i], &a.buckets[(size_t)bn * CAPB + idx]);
    }
  } else {
    GemmSh* G = reinterpret_cast<GemmSh*>(shraw);
    int gb = b - a.nplace;
    int ji = 3;
    if (gb < a.j[1].blk0) ji = 0;
    else if (gb < a.j[2].blk0) ji = 1;
    else if (gb < a.j[3].blk0) ji = 2;
    GJob J = a.j[ji];
    gemm_body(G, a.A0, a.nA, J.A1, a.Wb + J.wboff, J.attn, J.Z, J.ews,
              J.zbase, J.nrows, gb - J.blk0);
  }
}

// ---------------- scan of 512 bin counts -> bin bases ----------------
__global__ __launch_bounds__(512) void k_scan512(const int* __restrict__ gcur,
                                                 int* __restrict__ binbase){
  __shared__ int sh[512];
  int tid = threadIdx.x;
  int v = gcur[tid * GSTR];
  sh[tid] = v; __syncthreads();
  for (int o = 1; o < 512; o <<= 1){
    int u = (tid >= o) ? sh[tid - o] : 0;
    __syncthreads();
    sh[tid] += u;
    __syncthreads();
  }
  binbase[tid] = sh[tid] - v;   // exclusive
}

// ---------------- scatc: per-bin LDS CSR sort, coalesced u16 dump ----------------
__global__ __launch_bounds__(512) void k_scatc(const u32* __restrict__ buckets,
                                               const int* __restrict__ gcur,
                                               const int* __restrict__ binbase,
                                               const int* __restrict__ pb,
                                               int* __restrict__ offs,
                                               u16* __restrict__ edges){
  __shared__ u16 els[MAXB];
  __shared__ int pc[NSEGMAX + 1];
  __shared__ int sc[512];
  const int t = blockIdx.x;
  const int tid = threadIdx.x;
  const int base = binbase[t];
  int n = gcur[t * GSTR]; if (n > CAPB) n = CAPB;
  const int lo = pb[t], hi = pb[t + 1];
  const int nsl = hi - lo;

  for (int j = tid; j < nsl; j += 512) pc[j] = 0;
  __syncthreads();
  for (int i = tid; i < n; i += 512){
    u32 e = buckets[(size_t)t * CAPB + i];
    int srel = (int)(e >> 16);
    if (srel < nsl) atomicAdd(&pc[srel], 1);
  }
  __syncthreads();
  int carry = 0;
  for (int cb = 0; cb < nsl; cb += 512){
    int j = cb + tid;
    int v = (j < nsl) ? pc[j] : 0;
    sc[tid] = v; __syncthreads();
    for (int o = 1; o < 512; o <<= 1){
      int u = (tid >= o) ? sc[tid - o] : 0;
      __syncthreads();
      sc[tid] += u;
      __syncthreads();
    }
    if (j < nsl) pc[j] = carry + sc[tid] - v;
    carry += sc[511];
    __syncthreads();
  }
  for (int j = tid; j < nsl; j += 512) offs[lo + j] = base + pc[j];
  if (t == NBINS - 1 && tid == 0) offs[hi] = base + n;
  __syncthreads();

  for (int i = tid; i < n; i += 512){
    u32 e = buckets[(size_t)t * CAPB + i];
    int srel = (int)(e >> 16);
    if (srel < nsl){
      int pos = atomicAdd(&pc[srel], 1);
      els[pos] = (u16)(e & 0xffffu);
    }
  }
  __syncthreads();
  int st = base & 1;
  if (st && tid == 0) edges[base] = els[0];
  int m = n - st;
  int nh = m >> 1;
  u32* dst = (u32*)(edges + base + st);
  for (int i2 = tid; i2 < nh; i2 += 512){
    u32 v = ((u32)els[st + 2 * i2 + 1] << 16) | (u32)els[st + 2 * i2];
    __builtin_nontemporal_store(v, &dst[i2]);
  }
  if ((m & 1) && tid == 0) edges[base + n - 1] = els[n - 1];
}

// ---------------- wave-per-segment aggregation (students + exercises) ----------------
// 4-deep unrolled gather: four edge rows in flight per slot for MLP.
#define GATHER4(EW, Z, ZB, ACC, DS, BEG, END)                                   \
  {                                                                             \
    int i = (BEG) + slot;                                                       \
    for (; i + 12 < (END); i += 16){                                            \
      int r0 = (int)a.edges[i]      - (ZB);                                     \
      int r1 = (int)a.edges[i + 4]  - (ZB);                                     \
      int r2 = (int)a.edges[i + 8]  - (ZB);                                     \
      int r3 = (int)a.edges[i + 12] - (ZB);                                     \
      float w0 = (EW)[r0], w1 = (EW)[r1], w2 = (EW)[r2], w3 = (EW)[r3];         \
      bf16x8 z0 = *(const bf16x8*)((Z) + (size_t)r0 * KD + li * 8);             \
      bf16x8 z1 = *(const bf16x8*)((Z) + (size_t)r1 * KD + li * 8);             \
      bf16x8 z2 = *(const bf16x8*)((Z) + (size_t)r2 * KD + li * 8);             \
      bf16x8 z3 = *(const bf16x8*)((Z) + (size_t)r3 * KD + li * 8);             \
      (DS) += (w0 + w1) + (w2 + w3);                                            \
      _Pragma("unroll")                                                         \
      for (int j = 0; j < 8; ++j){                                              \
        (ACC)[j] = fmaf(w0, bf2f(z0[j]), (ACC)[j]);                             \
        (ACC)[j] = fmaf(w1, bf2f(z1[j]), (ACC)[j]);                             \
        (ACC)[j] = fmaf(w2, bf2f(z2[j]), (ACC)[j]);                             \
        (ACC)[j] = fmaf(w3, bf2f(z3[j]), (ACC)[j]);                             \
      }                                                                         \
    }                                                                           \
    for (; i < (END); i += 4){                                                  \
      int r0 = (int)a.edges[i] - (ZB);                                          \
      float w0 = (EW)[r0];                                                      \
      bf16x8 z0 = *(const bf16x8*)((Z) + (size_t)r0 * KD + li * 8);             \
      (DS) += w0;                                                               \
      _Pragma("unroll")                                                         \
      for (int j = 0; j < 8; ++j) (ACC)[j] = fmaf(w0, bf2f(z0[j]), (ACC)[j]);   \
    }                                                                           \
  }

struct AggArgs {
  const int* offs; const u16* edges;
  const float* ew_sfe; const __hip_bfloat16* z_sfe;
  const float* ew_efs; const __hip_bfloat16* z_efs;
  const float* ew_efk; const __hip_bfloat16* z_efk;
  const float* stu; const float* exer;
  float* out;
  const float* a0W; const float* a0b; const float* a1W; const float* a1b;
  int S, E;
};

__global__ __launch_bounds__(256) void k_aggW(AggArgs a){
  const int lane = threadIdx.x & 63;
  const int wave = threadIdx.x >> 6;
  const int li = lane & 15;
  const int slot = lane >> 4;
  const int gs = blockIdx.x * 4 + wave;
  if (gs >= a.S + a.E) return;

  if (gs < a.S){
    const int beg = a.offs[gs], end = a.offs[gs + 1];
    float acc[8];
#pragma unroll
    for (int j = 0; j < 8; ++j) acc[j] = 0.f;
    float ds = 0.f;
    GATHER4(a.ew_sfe, a.z_sfe, a.S, acc, ds, beg, end)
#pragma unroll
    for (int j = 0; j < 8; ++j){
      acc[j] += __shfl_xor(acc[j], 16, 64);
      acc[j] += __shfl_xor(acc[j], 32, 64);
    }
    ds += __shfl_xor(ds, 16, 64);
    ds += __shfl_xor(ds, 32, 64);
    float rden = (end > beg) ? 1.f / ds : 0.f;
    if (lane < 32){
      const size_t o = (size_t)gs * KD + li * 8 + slot * 4;
      const float* emb = a.stu + o;
      float4 v;
      v.x = emb[0] + acc[slot * 4 + 0] * rden;
      v.y = emb[1] + acc[slot * 4 + 1] * rden;
      v.z = emb[2] + acc[slot * 4 + 2] * rden;
      v.w = emb[3] + acc[slot * 4 + 3] * rden;
      *(float4*)(a.out + o) = v;
    }
  } else {
    const int e = gs - a.S;
    const int b1 = a.offs[a.S + e], e1 = a.offs[a.S + e + 1];
    const int b2 = a.offs[a.S + a.E + e], e2 = a.offs[a.S + a.E + e + 1];
    float acc1[8], acc2[8];
#pragma unroll
    for (int j = 0; j < 8; ++j){ acc1[j] = 0.f; acc2[j] = 0.f; }
    float ds1 = 0.f, ds2 = 0.f;
    GATHER4(a.ew_efs, a.z_efs, 0,   acc1, ds1, b1, e1)
    GATHER4(a.ew_efk, a.z_efk, a.E, acc2, ds2, b2, e2)
#pragma unroll
    for (int j = 0; j < 8; ++j){
      acc1[j] += __shfl_xor(acc1[j], 16, 64);
      acc1[j] += __shfl_xor(acc1[j], 32, 64);
      acc2[j] += __shfl_xor(acc2[j], 16, 64);
      acc2[j] += __shfl_xor(acc2[j], 32, 64);
    }
    ds1 += __shfl_xor(ds1, 16, 64); ds1 += __shfl_xor(ds1, 32, 64);
    ds2 += __shfl_xor(ds2, 16, 64); ds2 += __shfl_xor(ds2, 32, 64);
    float r1 = (e1 > b1) ? 1.f / ds1 : 0.f;
    float r2 = (e2 > b2) ? 1.f / ds2 : 0.f;
    float aw1[8], aw2[8];
#pragma unroll
    for (int j = 0; j < 8; ++j){ aw1[j] = acc1[j] * r1; aw2[j] = acc2[j] * r2; }

    float ex8[8];
    {
      float4 u0 = *(const float4*)(a.exer + (size_t)e * KD + li * 8);
      float4 u1 = *(const float4*)(a.exer + (size_t)e * KD + li * 8 + 4);
      ex8[0]=u0.x; ex8[1]=u0.y; ex8[2]=u0.z; ex8[3]=u0.w;
      ex8[4]=u1.x; ex8[5]=u1.y; ex8[6]=u1.z; ex8[7]=u1.w;
    }
    float q0 = 0.f, q1 = 0.f;
#pragma unroll
    for (int j = 0; j < 8; ++j){
      q0 += ex8[j] * a.a0W[li * 8 + j] + aw1[j] * a.a0W[KD + li * 8 + j];
      q1 += ex8[j] * a.a1W[li * 8 + j] + aw2[j] * a.a1W[KD + li * 8 + j];
    }
#pragma unroll
    for (int o = 1; o < 16; o <<= 1){
      q0 += __shfl_xor(q0, o, 64);
      q1 += __shfl_xor(q1, o, 64);
    }
    float sc0 = q0 + a.a0b[0], sc1 = q1 + a.a1b[0];
    float mx = fmaxf(sc0, sc1);
    float w0 = __expf(sc0 - mx), w1 = __expf(sc1 - mx);
    float inv = 1.f / (w0 + w1);
    w0 *= inv; w1 *= inv;
    if (lane < 32){
      const size_t o = (size_t)gs * KD + li * 8 + slot * 4;
      float4 v;
#pragma unroll
      for (int q = 0; q < 4; ++q){
        int j = slot * 4 + q;
        ((float*)&v)[q] = ex8[j] + w0 * aw1[j] + w1 * aw2[j];
      }
      *(float4*)(a.out + o) = v;
    }
  }
}

// ---------------- knowledge aggregation: block-per-seg, 4-deep ----------------
__global__ __launch_bounds__(512) void k_aggK(const int* __restrict__ offs, int segbase,
                                              const u16* __restrict__ edges,
                                              const float* __restrict__ ews,
                                              const __hip_bfloat16* __restrict__ Z,
                                              const float* __restrict__ kn,
                                              float* __restrict__ out){
  __shared__ float sred[8];
  __shared__ float lacc[8][KD];
  const int tid = threadIdx.x;
  const int wave = tid >> 6, lane = tid & 63;
  const int sub = lane >> 4, li = lane & 15;
  const int seg = segbase + blockIdx.x;
  const int beg = offs[seg], end = offs[seg + 1];

  float acc[8];
#pragma unroll
  for (int j = 0; j < 8; ++j) acc[j] = 0.f;
  float ds = 0.f;
  const int slot = wave * 4 + sub;
  {
    int i = beg + slot;
    for (; i + 96 < end; i += 128){
      int r0 = (int)edges[i];
      int r1 = (int)edges[i + 32];
      int r2 = (int)edges[i + 64];
      int r3 = (int)edges[i + 96];
      float w0 = ews[r0], w1 = ews[r1], w2 = ews[r2], w3 = ews[r3];
      bf16x8 z0 = *(const bf16x8*)(Z + (size_t)r0 * KD + li * 8);
      bf16x8 z1 = *(const bf16x8*)(Z + (size_t)r1 * KD + li * 8);
      bf16x8 z2 = *(const bf16x8*)(Z + (size_t)r2 * KD + li * 8);
      bf16x8 z3 = *(const bf16x8*)(Z + (size_t)r3 * KD + li * 8);
      ds += (w0 + w1) + (w2 + w3);
#pragma unroll
      for (int j = 0; j < 8; ++j){
        acc[j] = fmaf(w0, bf2f(z0[j]), acc[j]);
        acc[j] = fmaf(w1, bf2f(z1[j]), acc[j]);
        acc[j] = fmaf(w2, bf2f(z2[j]), acc[j]);
        acc[j] = fmaf(w3, bf2f(z3[j]), acc[j]);
      }
    }
    for (; i < end; i += 32){
      int r0 = (int)edges[i];
      float w0 = ews[r0];
      bf16x8 z0 = *(const bf16x8*)(Z + (size_t)r0 * KD + li * 8);
      ds += w0;
#pragma unroll
      for (int j = 0; j < 8; ++j) acc[j] = fmaf(w0, bf2f(z0[j]), acc[j]);
    }
  }
#pragma unroll
  for (int j = 0; j < 8; ++j){
    acc[j] += __shfl_xor(acc[j], 16, 64);
    acc[j] += __shfl_xor(acc[j], 32, 64);
  }
  ds += __shfl_xor(ds, 16, 64);
  ds += __shfl_xor(ds, 32, 64);
  if (lane == 0) sred[wave] = ds;
  if (sub == 0){
    f32x4 v0, v1;
#pragma unroll
    for (int j = 0; j < 4; ++j){ v0[j] = acc[j]; v1[j] = acc[4 + j]; }
    *(f32x4*)&lacc[wave][li * 8]     = v0;
    *(f32x4*)&lacc[wave][li * 8 + 4] = v1;
  }
  __syncthreads();
  if (tid < KD){
    float dsum = 0.f;
#pragma unroll
    for (int wv = 0; wv < 8; ++wv) dsum += sred[wv];
    float s = 0.f;
#pragma unroll
    for (int wv = 0; wv < 8; ++wv) s += lacc[wv][tid];
    float rden = (end > beg) ? 1.f / dsum : 0.f;
    out[(size_t)blockIdx.x * KD + tid] = kn[(size_t)blockIdx.x * KD + tid] + s * rden;
  }
}

extern "C" void kernel_launch(void* const* d_in, const int* in_sizes, int n_in,
                              void* d_out, int out_size, void* d_ws, size_t ws_size,
                              hipStream_t stream){
  const int S  = in_sizes[0] / KD;     // 40000
  const int E  = in_sizes[1] / KD;     // 18000
  const int KN = in_sizes[2] / KD;     // 128
  const int nse = in_sizes[19];        // 1.5M
  const int nek = in_sizes[23];        // 180K

  const float* stu  = (const float*)d_in[0];
  const float* exer = (const float*)d_in[1];
  const float* kn   = (const float*)d_in[2];
  const float* sfe_fcW = (const float*)d_in[3];  const float* sfe_attn = (const float*)d_in[4];
  const float* efs_fcW = (const float*)d_in[5];  const float* efs_attn = (const float*)d_in[6];
  const float* efk_fcW = (const float*)d_in[7];  const float* efk_attn = (const float*)d_in[8];
  const float* kfe_fcW = (const float*)d_in[9];  const float* kfe_attn = (const float*)d_in[10];
  const float* ea0W = (const float*)d_in[13]; const float* ea0b = (const float*)d_in[14];
  const float* ea1W = (const float*)d_in[15]; const float* ea1b = (const float*)d_in[16];
  const int* sfe_src = (const int*)d_in[19]; const int* sfe_dst = (const int*)d_in[20];
  const int* efs_src = (const int*)d_in[21]; const int* efs_dst = (const int*)d_in[22];
  const int* efk_src = (const int*)d_in[23]; const int* efk_dst = (const int*)d_in[24];
  const int* kfe_src = (const int*)d_in[25]; const int* kfe_dst = (const int*)d_in[26];
  float* out = (float*)d_out;

  // ---- workspace carve-up ----
  char* w = (char*)d_ws;
  auto alloc = [&](size_t bytes) -> char* {
    char* p = w; w += (bytes + 255) & ~(size_t)255; return p;
  };
  short* Wb               = (short*)alloc((size_t)4 * 16384 * 2);
  __hip_bfloat16* z_sfe   = (__hip_bfloat16*)alloc((size_t)E  * KD * 2);
  __hip_bfloat16* z_efs   = (__hip_bfloat16*)alloc((size_t)S  * KD * 2);
  __hip_bfloat16* z_efk   = (__hip_bfloat16*)alloc((size_t)KN * KD * 2);
  __hip_bfloat16* z_kfe   = (__hip_bfloat16*)alloc((size_t)E  * KD * 2);
  float* ew_sfe = (float*)alloc((size_t)E  * 4);
  float* ew_efs = (float*)alloc((size_t)S  * 4);
  float* ew_efk = (float*)alloc((size_t)KN * 4);
  float* ew_kfe = (float*)alloc((size_t)E  * 4);
  const int NSEG = S + E + E + KN;     // 76128
  const size_t TOTE = 2 * (size_t)nse + 2 * (size_t)nek;
  const int NPLACE = (int)((TOTE + CHUNKP - 1) / CHUNKP);   // ~1641
  int* pb512   = (int*)alloc((NBINS + 1) * 4);
  int* gcur    = (int*)alloc((size_t)NBINS * GSTR * 4);
  int* binbase = (int*)alloc(NBINS * 4);
  int* offs    = (int*)alloc((size_t)(NSEG + 1) * 4);
  u32* buckets = (u32*)alloc((size_t)NBINS * CAPB * 4);
  u16* edges   = (u16*)alloc(TOTE * 2);

  hipMemsetAsync(gcur, 0, (size_t)NBINS * GSTR * 4, stream);

  BinParams bp;
  bp.Cb[0] = 0; bp.Cb[1] = nse; bp.Cb[2] = 2L * nse; bp.Cb[3] = 2L * nse + nek;
  bp.base[0] = 0; bp.base[1] = S; bp.base[2] = S + E; bp.base[3] = S + 2 * E;
  bp.dr[0] = (double)nse / S; bp.dr[1] = (double)nse / E;
  bp.dr[2] = (double)nek / E; bp.dr[3] = (double)nek / KN;
  bp.dbin = (double)NBINS / (double)TOTE;
  bp.nseg = NSEG;

  k_pb512<<<1, 1024, 0, stream>>>(bp, pb512);
  k_cvt_w<<<256, 256, 0, stream>>>(sfe_fcW, efs_fcW, efk_fcW, kfe_fcW, Wb);

  const int nbE = (E + 63) / 64, nbS = (S + 63) / 64, nbK = (KN + 63) / 64;
  MegaArgs ma;
  ma.d0 = sfe_dst; ma.s0 = sfe_src; ma.d1 = efs_dst; ma.s1 = efs_src;
  ma.d2 = efk_dst; ma.s2 = efk_src; ma.d3 = kfe_dst; ma.s3 = kfe_src;
  ma.nse = nse; ma.nek = nek; ma.rebase23 = S + E; ma.nplace = NPLACE;
  ma.buckets = buckets; ma.gcur = gcur; ma.pb = pb512; ma.bp = bp;
  ma.A0 = exer; ma.nA = E; ma.Wb = Wb;
  ma.j[0] = { stu, sfe_attn, z_sfe, ew_sfe, S, E,  0,               0 };
  ma.j[1] = { stu, efs_attn, z_efs, ew_efs, 0, S,  nbE,             16384 };
  ma.j[2] = { kn,  efk_attn, z_efk, ew_efk, E, KN, nbE + nbS,       32768 };
  ma.j[3] = { kn,  kfe_attn, z_kfe, ew_kfe, 0, E,  nbE + nbS + nbK, 49152 };
  k_megaF<<<NPLACE + nbE + nbS + nbK + nbE, 256, 0, stream>>>(ma);

  k_scan512<<<1, 512, 0, stream>>>(gcur, binbase);
  k_scatc<<<NBINS, 512, 0, stream>>>(buckets, gcur, binbase, pb512, offs, edges);

  k_aggK<<<KN, 512, 0, stream>>>(offs, S + 2 * E, edges, ew_kfe, z_kfe,
                                 kn, out + (size_t)(S + E) * KD);

  AggArgs aa;
  aa.offs = offs; aa.edges = edges;
  aa.ew_sfe = ew_sfe; aa.z_sfe = z_sfe;
  aa.ew_efs = ew_efs; aa.z_efs = z_efs;
  aa.ew_efk = ew_efk; aa.z_efk = z_efk;
  aa.stu = stu; aa.exer = exer; aa.out = out;
  aa.a0W = ea0W; aa.a0b = ea0b; aa.a1W = ea1W; aa.a1b = ea1b;
  aa.S = S; aa.E = E;
  k_aggW<<<(S + E + 3) / 4, 256, 0, stream>>>(aa);
}

// Round 21
// 229.330 us; speedup vs baseline: 1.0514x; 1.0514x over previous
//
#include <hip/hip_runtime.h>
#include <hip/hip_bf16.h>

using f32x4  = __attribute__((ext_vector_type(4))) float;
using bf16x8 = __attribute__((ext_vector_type(8))) short;
typedef unsigned int u32;
typedef unsigned short u16;

#define KD 128
#define NBINS 256       // fewer, fatter bins: 16-entry (64B) dump runs
#define CHUNKP 4096     // place chunk (LDS-resident); 16 entries/thread
#define EPT 16
#define CAPB 16384
#define MAXB 16384
#define NSEGMAX 1536
#define GSTR 16         // gcur padding stride (64B per bin)

__device__ inline float bf2f(short s){
  return __uint_as_float(((u32)(u16)s) << 16);
}

struct BinParams {
  long Cb[4]; int base[4]; double dr[4]; double dbin; int nseg;
};

__device__ inline int bin_of(int seg, const BinParams& bp){
  int r = (seg >= bp.base[1]) + (seg >= bp.base[2]) + (seg >= bp.base[3]);
  long ep = bp.Cb[r] + (long)((double)(seg - bp.base[r]) * bp.dr[r]);
  int b = (int)((double)ep * bp.dbin);
  return (b > NBINS - 1) ? (NBINS - 1) : b;
}

// ---------------- pb256: bin -> first seg ----------------
__global__ void k_pb256(BinParams bp, int* __restrict__ pb){
  int t = blockIdx.x * blockDim.x + threadIdx.x;
  if (t > NBINS) return;
  if (t == 0){ pb[0] = 0; return; }
  if (t == NBINS){ pb[NBINS] = bp.nseg; return; }
  int lo = 0, hi = bp.nseg;
  while (lo < hi){
    int mid = (lo + hi) >> 1;
    if (bin_of(mid, bp) >= t) hi = mid; else lo = mid + 1;
  }
  pb[t] = lo;
}

// ---------------- weight convert ----------------
__global__ __launch_bounds__(256) void k_cvt_w(const float* __restrict__ w0,
                                               const float* __restrict__ w1,
                                               const float* __restrict__ w2,
                                               const float* __restrict__ w3,
                                               short* __restrict__ out){
  int i = blockIdx.x * 256 + threadIdx.x;
  const float* src = (i < 16384) ? w0 : (i < 32768) ? w1 : (i < 49152) ? w2 : w3;
  float v = src[i & 16383];
  __hip_bfloat16 b = __float2bfloat16(v);
  out[i] = __builtin_bit_cast(short, b);
}

// ---------------- shared-memory overlay structs (256-thread fused kernel) ----------------
struct PlaceSh {
  u32 sorted[CHUNKP];   // 16KB
  u16 sbid[CHUNKP];     // 8KB
  int cnt[NBINS];
  int lbase[NBINS];
  int lpos[NBINS];
  int pbL[NBINS];       // 4KB for the 4 arrays
  int sc[256];          // 1KB
};                      // ~29KB
struct GemmSh { short zst[4][16][136]; };   // 17KB

// ---------------- GEMM z = h @ W^T (+ ews = exp(z . attn)) ----------------
struct GJob { const float* A1; const float* attn; __hip_bfloat16* Z; float* ews;
              int zbase, nrows, blk0, wboff; };

__device__ void gemm_body(GemmSh* g,
                          const float* __restrict__ A0, int nA,
                          const float* __restrict__ A1,
                          const short* __restrict__ Wb, const float* __restrict__ attn,
                          __hip_bfloat16* __restrict__ Z, float* __restrict__ ews,
                          int zbase, int nrows, int blk)
{
  const int wave = threadIdx.x >> 6, lane = threadIdx.x & 63;
  const int lr = lane & 15, lk = lane >> 4;
  const int row0 = blk * 64 + wave * 16;

  bf16x8 afrag[4];
  {
    int r = row0 + lr;
    bool rv = (r < nrows);
    int node = zbase + r;
    const float* ap = A0;
    if (rv) ap = (node < nA) ? (A0 + (size_t)node * KD) : (A1 + (size_t)(node - nA) * KD);
#pragma unroll
    for (int t = 0; t < 4; ++t){
      float x[8];
      if (rv){
        float4 u0 = *(const float4*)(ap + t * 32 + lk * 8);
        float4 u1 = *(const float4*)(ap + t * 32 + lk * 8 + 4);
        x[0]=u0.x; x[1]=u0.y; x[2]=u0.z; x[3]=u0.w;
        x[4]=u1.x; x[5]=u1.y; x[6]=u1.z; x[7]=u1.w;
      } else {
#pragma unroll
        for (int j = 0; j < 8; ++j) x[j] = 0.f;
      }
      bf16x8 af;
#pragma unroll
      for (int j = 0; j < 8; ++j){
        __hip_bfloat16 b = __float2bfloat16(x[j]);
        af[j] = __builtin_bit_cast(short, b);
      }
      afrag[t] = af;
    }
  }

  f32x4 acc[8];
#pragma unroll
  for (int c = 0; c < 8; ++c){ acc[c][0]=0.f; acc[c][1]=0.f; acc[c][2]=0.f; acc[c][3]=0.f; }

#pragma unroll
  for (int c = 0; c < 8; ++c){
#pragma unroll
    for (int t = 0; t < 4; ++t){
      bf16x8 bf = *(const bf16x8*)(Wb + (c * 16 + lr) * KD + t * 32 + lk * 8);
      acc[c] = __builtin_amdgcn_mfma_f32_16x16x32_bf16(afrag[t], bf, acc[c], 0, 0, 0);
    }
  }

  float p[4] = {0.f, 0.f, 0.f, 0.f};
#pragma unroll
  for (int c = 0; c < 8; ++c){
    float av = attn[c * 16 + lr];
#pragma unroll
    for (int q = 0; q < 4; ++q){
      p[q] += acc[c][q] * av;
      g->zst[wave][lk * 4 + q][c * 16 + lr] =
          __builtin_bit_cast(short, __float2bfloat16(acc[c][q]));
    }
  }
#pragma unroll
  for (int q = 0; q < 4; ++q){
#pragma unroll
    for (int o = 1; o < 16; o <<= 1) p[q] += __shfl_xor(p[q], o, 64);
  }
  if (lr == 0){
#pragma unroll
    for (int q = 0; q < 4; ++q){
      int r = row0 + lk * 4 + q;
      if (r < nrows) ews[r] = __expf(p[q]);   // max-shift cancels in segment softmax
    }
  }
  __syncthreads();
#pragma unroll
  for (int pq = 0; pq < 4; ++pq){
    int row = pq * 4 + (lane >> 4);
    int col8 = (lane & 15) * 8;
    bf16x8 v = *(const bf16x8*)&g->zst[wave][row][col8];
    int r = row0 + row;
    if (r < nrows) *(bf16x8*)(Z + (size_t)r * KD + col8) = v;
  }
}

// ---------------- megaF: place blocks + gemm blocks (256 threads, LDS overlay) ----------------
struct MegaArgs {
  const int* d0; const int* s0; const int* d1; const int* s1;
  const int* d2; const int* s2; const int* d3; const int* s3;
  int nse, nek, rebase23, nplace;
  u32* buckets;
  int* gcur;              // padded: bin j at gcur[j*GSTR]
  const int* pb;
  BinParams bp;
  const float* A0; int nA;
  const short* Wb;
  GJob j[4];
};

__global__ __launch_bounds__(256) void k_megaF(MegaArgs a){
  __shared__ alignas(16) char shraw[sizeof(PlaceSh)];
  const int tid = threadIdx.x;
  const int b = blockIdx.x;
  if (b < a.nplace){
    PlaceSh& P = *reinterpret_cast<PlaceSh*>(shraw);
    if (tid < NBINS){ P.cnt[tid] = 0; P.pbL[tid] = a.pb[tid]; }
    __syncthreads();
    const long total = 2L * a.nse + 2L * a.nek;
    long c0 = (long)b * CHUNKP;
    long c1 = c0 + CHUNKP; if (c1 > total) c1 = total;

    // pass A: load once, stage entries in registers, build local hist
    u32 re[EPT];
    int rbn[EPT];
#pragma unroll
    for (int it = 0; it < EPT; ++it){
      long i = c0 + (long)it * 256 + tid;
      rbn[it] = -1;
      if (i < c1){
        long k = i; const int* dp; const int* sp; int rb;
        if (k < a.nse){ dp = a.d0; sp = a.s0; rb = 0; }
        else if ((k -= a.nse) < a.nse){ dp = a.d1; sp = a.s1; rb = 0; }
        else if ((k -= a.nse) < a.nek){ dp = a.d2; sp = a.s2; rb = a.rebase23; }
        else { k -= a.nek; dp = a.d3; sp = a.s3; rb = a.rebase23; }
        int seg = dp[k] + rb;
        int bn = bin_of(seg, a.bp);
        re[it]  = ((u32)(seg - P.pbL[bn]) << 16) | (u32)sp[k];
        rbn[it] = bn;
        atomicAdd(&P.cnt[bn], 1);
      }
    }
    __syncthreads();
    // exclusive scan (256 bins, 256 threads, single round)
    {
      int v = P.cnt[tid];
      P.sc[tid] = v; __syncthreads();
      for (int o = 1; o < 256; o <<= 1){
        int u = (tid >= o) ? P.sc[tid - o] : 0;
        __syncthreads();
        P.sc[tid] += u;
        __syncthreads();
      }
      P.lbase[tid] = P.sc[tid] - v;
      P.lpos[tid]  = P.sc[tid] - v;
    }
    __syncthreads();
    // reserve global runs (padded gcur); cnt[] becomes gbs[]
    if (tid < NBINS){
      int c = P.cnt[tid];
      P.cnt[tid] = c ? atomicAdd(&a.gcur[tid * GSTR], c) : 0;
    }
    __syncthreads();
    // pass B: scatter from registers into LDS (sorted by bin)
#pragma unroll
    for (int it = 0; it < EPT; ++it){
      if (rbn[it] >= 0){
        int p = atomicAdd(&P.lpos[rbn[it]], 1);
        P.sorted[p] = re[it];
        P.sbid[p] = (u16)rbn[it];
      }
    }
    __syncthreads();
    // coalesced-run dump into per-bin buckets (avg 16-entry = 64B runs)
    int n = (int)(c1 - c0);
    for (int i = tid; i < n; i += 256){
      int bn = P.sbid[i];
      int idx = P.cnt[bn] + (i - P.lbase[bn]);
      if (idx < CAPB)
        __builtin_nontemporal_store(P.sorted[i], &a.buckets[(size_t)bn * CAPB + idx]);
    }
  } else {
    GemmSh* G = reinterpret_cast<GemmSh*>(shraw);
    int gb = b - a.nplace;
    int ji = 3;
    if (gb < a.j[1].blk0) ji = 0;
    else if (gb < a.j[2].blk0) ji = 1;
    else if (gb < a.j[3].blk0) ji = 2;
    GJob J = a.j[ji];
    gemm_body(G, a.A0, a.nA, J.A1, a.Wb + J.wboff, J.attn, J.Z, J.ews,
              J.zbase, J.nrows, gb - J.blk0);
  }
}

// ---------------- scan of 256 bin counts -> bin bases ----------------
__global__ __launch_bounds__(256) void k_scan256(const int* __restrict__ gcur,
                                                 int* __restrict__ binbase){
  __shared__ int sh[256];
  int tid = threadIdx.x;
  int v = gcur[tid * GSTR];
  sh[tid] = v; __syncthreads();
  for (int o = 1; o < 256; o <<= 1){
    int u = (tid >= o) ? sh[tid - o] : 0;
    __syncthreads();
    sh[tid] += u;
    __syncthreads();
  }
  binbase[tid] = sh[tid] - v;   // exclusive
}

// ---------------- scatc: per-bin LDS CSR sort, coalesced u16 dump ----------------
__global__ __launch_bounds__(512) void k_scatc(const u32* __restrict__ buckets,
                                               const int* __restrict__ gcur,
                                               const int* __restrict__ binbase,
                                               const int* __restrict__ pb,
                                               int* __restrict__ offs,
                                               u16* __restrict__ edges){
  __shared__ u16 els[MAXB];          // 32KB
  __shared__ int pc[NSEGMAX + 1];    // 6.1KB
  __shared__ int sc[512];
  const int t = blockIdx.x;
  const int tid = threadIdx.x;
  const int base = binbase[t];
  int n = gcur[t * GSTR]; if (n > CAPB) n = CAPB;
  const int lo = pb[t], hi = pb[t + 1];
  const int nsl = hi - lo;

  for (int j = tid; j < nsl; j += 512) pc[j] = 0;
  __syncthreads();
  for (int i = tid; i < n; i += 512){
    u32 e = buckets[(size_t)t * CAPB + i];
    int srel = (int)(e >> 16);
    if (srel < nsl) atomicAdd(&pc[srel], 1);
  }
  __syncthreads();
  int carry = 0;
  for (int cb = 0; cb < nsl; cb += 512){
    int j = cb + tid;
    int v = (j < nsl) ? pc[j] : 0;
    sc[tid] = v; __syncthreads();
    for (int o = 1; o < 512; o <<= 1){
      int u = (tid >= o) ? sc[tid - o] : 0;
      __syncthreads();
      sc[tid] += u;
      __syncthreads();
    }
    if (j < nsl) pc[j] = carry + sc[tid] - v;
    carry += sc[511];
    __syncthreads();
  }
  for (int j = tid; j < nsl; j += 512) offs[lo + j] = base + pc[j];
  if (t == NBINS - 1 && tid == 0) offs[hi] = base + n;
  __syncthreads();

  for (int i = tid; i < n; i += 512){
    u32 e = buckets[(size_t)t * CAPB + i];
    int srel = (int)(e >> 16);
    if (srel < nsl){
      int pos = atomicAdd(&pc[srel], 1);
      els[pos] = (u16)(e & 0xffffu);
    }
  }
  __syncthreads();
  int st = base & 1;
  if (st && tid == 0) edges[base] = els[0];
  int m = n - st;
  int nh = m >> 1;
  u32* dst = (u32*)(edges + base + st);
  for (int i2 = tid; i2 < nh; i2 += 512){
    u32 v = ((u32)els[st + 2 * i2 + 1] << 16) | (u32)els[st + 2 * i2];
    __builtin_nontemporal_store(v, &dst[i2]);
  }
  if ((m & 1) && tid == 0) edges[base + n - 1] = els[n - 1];
}

// ---------------- wave-per-segment aggregation (students + exercises) ----------------
// 4-deep unrolled gather: four edge rows in flight per slot for MLP.
#define GATHER4(EW, Z, ZB, ACC, DS, BEG, END)                                   \
  {                                                                             \
    int i = (BEG) + slot;                                                       \
    for (; i + 12 < (END); i += 16){                                            \
      int r0 = (int)a.edges[i]      - (ZB);                                     \
      int r1 = (int)a.edges[i + 4]  - (ZB);                                     \
      int r2 = (int)a.edges[i + 8]  - (ZB);                                     \
      int r3 = (int)a.edges[i + 12] - (ZB);                                     \
      float w0 = (EW)[r0], w1 = (EW)[r1], w2 = (EW)[r2], w3 = (EW)[r3];         \
      bf16x8 z0 = *(const bf16x8*)((Z) + (size_t)r0 * KD + li * 8);             \
      bf16x8 z1 = *(const bf16x8*)((Z) + (size_t)r1 * KD + li * 8);             \
      bf16x8 z2 = *(const bf16x8*)((Z) + (size_t)r2 * KD + li * 8);             \
      bf16x8 z3 = *(const bf16x8*)((Z) + (size_t)r3 * KD + li * 8);             \
      (DS) += (w0 + w1) + (w2 + w3);                                            \
      _Pragma("unroll")                                                         \
      for (int j = 0; j < 8; ++j){                                              \
        (ACC)[j] = fmaf(w0, bf2f(z0[j]), (ACC)[j]);                             \
        (ACC)[j] = fmaf(w1, bf2f(z1[j]), (ACC)[j]);                             \
        (ACC)[j] = fmaf(w2, bf2f(z2[j]), (ACC)[j]);                             \
        (ACC)[j] = fmaf(w3, bf2f(z3[j]), (ACC)[j]);                             \
      }                                                                         \
    }                                                                           \
    for (; i < (END); i += 4){                                                  \
      int r0 = (int)a.edges[i] - (ZB);                                          \
      float w0 = (EW)[r0];                                                      \
      bf16x8 z0 = *(const bf16x8*)((Z) + (size_t)r0 * KD + li * 8);             \
      (DS) += w0;                                                               \
      _Pragma("unroll")                                                         \
      for (int j = 0; j < 8; ++j) (ACC)[j] = fmaf(w0, bf2f(z0[j]), (ACC)[j]);   \
    }                                                                           \
  }

struct AggArgs {
  const int* offs; const u16* edges;
  const float* ew_sfe; const __hip_bfloat16* z_sfe;
  const float* ew_efs; const __hip_bfloat16* z_efs;
  const float* ew_efk; const __hip_bfloat16* z_efk;
  const float* stu; const float* exer;
  float* out;
  const float* a0W; const float* a0b; const float* a1W; const float* a1b;
  int S, E;
};

__global__ __launch_bounds__(256) void k_aggW(AggArgs a){
  const int lane = threadIdx.x & 63;
  const int wave = threadIdx.x >> 6;
  const int li = lane & 15;
  const int slot = lane >> 4;
  const int gs = blockIdx.x * 4 + wave;
  if (gs >= a.S + a.E) return;

  if (gs < a.S){
    const int beg = a.offs[gs], end = a.offs[gs + 1];
    float acc[8];
#pragma unroll
    for (int j = 0; j < 8; ++j) acc[j] = 0.f;
    float ds = 0.f;
    GATHER4(a.ew_sfe, a.z_sfe, a.S, acc, ds, beg, end)
#pragma unroll
    for (int j = 0; j < 8; ++j){
      acc[j] += __shfl_xor(acc[j], 16, 64);
      acc[j] += __shfl_xor(acc[j], 32, 64);
    }
    ds += __shfl_xor(ds, 16, 64);
    ds += __shfl_xor(ds, 32, 64);
    float rden = (end > beg) ? 1.f / ds : 0.f;
    if (lane < 32){
      const size_t o = (size_t)gs * KD + li * 8 + slot * 4;
      const float* emb = a.stu + o;
      float4 v;
      v.x = emb[0] + acc[slot * 4 + 0] * rden;
      v.y = emb[1] + acc[slot * 4 + 1] * rden;
      v.z = emb[2] + acc[slot * 4 + 2] * rden;
      v.w = emb[3] + acc[slot * 4 + 3] * rden;
      *(float4*)(a.out + o) = v;
    }
  } else {
    const int e = gs - a.S;
    const int b1 = a.offs[a.S + e], e1 = a.offs[a.S + e + 1];
    const int b2 = a.offs[a.S + a.E + e], e2 = a.offs[a.S + a.E + e + 1];
    float acc1[8], acc2[8];
#pragma unroll
    for (int j = 0; j < 8; ++j){ acc1[j] = 0.f; acc2[j] = 0.f; }
    float ds1 = 0.f, ds2 = 0.f;
    GATHER4(a.ew_efs, a.z_efs, 0,   acc1, ds1, b1, e1)
    GATHER4(a.ew_efk, a.z_efk, a.E, acc2, ds2, b2, e2)
#pragma unroll
    for (int j = 0; j < 8; ++j){
      acc1[j] += __shfl_xor(acc1[j], 16, 64);
      acc1[j] += __shfl_xor(acc1[j], 32, 64);
      acc2[j] += __shfl_xor(acc2[j], 16, 64);
      acc2[j] += __shfl_xor(acc2[j], 32, 64);
    }
    ds1 += __shfl_xor(ds1, 16, 64); ds1 += __shfl_xor(ds1, 32, 64);
    ds2 += __shfl_xor(ds2, 16, 64); ds2 += __shfl_xor(ds2, 32, 64);
    float r1 = (e1 > b1) ? 1.f / ds1 : 0.f;
    float r2 = (e2 > b2) ? 1.f / ds2 : 0.f;
    float aw1[8], aw2[8];
#pragma unroll
    for (int j = 0; j < 8; ++j){ aw1[j] = acc1[j] * r1; aw2[j] = acc2[j] * r2; }

    float ex8[8];
    {
      float4 u0 = *(const float4*)(a.exer + (size_t)e * KD + li * 8);
      float4 u1 = *(const float4*)(a.exer + (size_t)e * KD + li * 8 + 4);
      ex8[0]=u0.x; ex8[1]=u0.y; ex8[2]=u0.z; ex8[3]=u0.w;
      ex8[4]=u1.x; ex8[5]=u1.y; ex8[6]=u1.z; ex8[7]=u1.w;
    }
    float q0 = 0.f, q1 = 0.f;
#pragma unroll
    for (int j = 0; j < 8; ++j){
      q0 += ex8[j] * a.a0W[li * 8 + j] + aw1[j] * a.a0W[KD + li * 8 + j];
      q1 += ex8[j] * a.a1W[li * 8 + j] + aw2[j] * a.a1W[KD + li * 8 + j];
    }
#pragma unroll
    for (int o = 1; o < 16; o <<= 1){
      q0 += __shfl_xor(q0, o, 64);
      q1 += __shfl_xor(q1, o, 64);
    }
    float sc0 = q0 + a.a0b[0], sc1 = q1 + a.a1b[0];
    float mx = fmaxf(sc0, sc1);
    float w0 = __expf(sc0 - mx), w1 = __expf(sc1 - mx);
    float inv = 1.f / (w0 + w1);
    w0 *= inv; w1 *= inv;
    if (lane < 32){
      const size_t o = (size_t)gs * KD + li * 8 + slot * 4;
      float4 v;
#pragma unroll
      for (int q = 0; q < 4; ++q){
        int j = slot * 4 + q;
        ((float*)&v)[q] = ex8[j] + w0 * aw1[j] + w1 * aw2[j];
      }
      *(float4*)(a.out + o) = v;
    }
  }
}

// ---------------- knowledge aggregation: block-per-seg, 4-deep ----------------
__global__ __launch_bounds__(512) void k_aggK(const int* __restrict__ offs, int segbase,
                                              const u16* __restrict__ edges,
                                              const float* __restrict__ ews,
                                              const __hip_bfloat16* __restrict__ Z,
                                              const float* __restrict__ kn,
                                              float* __restrict__ out){
  __shared__ float sred[8];
  __shared__ float lacc[8][KD];
  const int tid = threadIdx.x;
  const int wave = tid >> 6, lane = tid & 63;
  const int sub = lane >> 4, li = lane & 15;
  const int seg = segbase + blockIdx.x;
  const int beg = offs[seg], end = offs[seg + 1];

  float acc[8];
#pragma unroll
  for (int j = 0; j < 8; ++j) acc[j] = 0.f;
  float ds = 0.f;
  const int slot = wave * 4 + sub;
  {
    int i = beg + slot;
    for (; i + 96 < end; i += 128){
      int r0 = (int)edges[i];
      int r1 = (int)edges[i + 32];
      int r2 = (int)edges[i + 64];
      int r3 = (int)edges[i + 96];
      float w0 = ews[r0], w1 = ews[r1], w2 = ews[r2], w3 = ews[r3];
      bf16x8 z0 = *(const bf16x8*)(Z + (size_t)r0 * KD + li * 8);
      bf16x8 z1 = *(const bf16x8*)(Z + (size_t)r1 * KD + li * 8);
      bf16x8 z2 = *(const bf16x8*)(Z + (size_t)r2 * KD + li * 8);
      bf16x8 z3 = *(const bf16x8*)(Z + (size_t)r3 * KD + li * 8);
      ds += (w0 + w1) + (w2 + w3);
#pragma unroll
      for (int j = 0; j < 8; ++j){
        acc[j] = fmaf(w0, bf2f(z0[j]), acc[j]);
        acc[j] = fmaf(w1, bf2f(z1[j]), acc[j]);
        acc[j] = fmaf(w2, bf2f(z2[j]), acc[j]);
        acc[j] = fmaf(w3, bf2f(z3[j]), acc[j]);
      }
    }
    for (; i < end; i += 32){
      int r0 = (int)edges[i];
      float w0 = ews[r0];
      bf16x8 z0 = *(const bf16x8*)(Z + (size_t)r0 * KD + li * 8);
      ds += w0;
#pragma unroll
      for (int j = 0; j < 8; ++j) acc[j] = fmaf(w0, bf2f(z0[j]), acc[j]);
    }
  }
#pragma unroll
  for (int j = 0; j < 8; ++j){
    acc[j] += __shfl_xor(acc[j], 16, 64);
    acc[j] += __shfl_xor(acc[j], 32, 64);
  }
  ds += __shfl_xor(ds, 16, 64);
  ds += __shfl_xor(ds, 32, 64);
  if (lane == 0) sred[wave] = ds;
  if (sub == 0){
    f32x4 v0, v1;
#pragma unroll
    for (int j = 0; j < 4; ++j){ v0[j] = acc[j]; v1[j] = acc[4 + j]; }
    *(f32x4*)&lacc[wave][li * 8]     = v0;
    *(f32x4*)&lacc[wave][li * 8 + 4] = v1;
  }
  __syncthreads();
  if (tid < KD){
    float dsum = 0.f;
#pragma unroll
    for (int wv = 0; wv < 8; ++wv) dsum += sred[wv];
    float s = 0.f;
#pragma unroll
    for (int wv = 0; wv < 8; ++wv) s += lacc[wv][tid];
    float rden = (end > beg) ? 1.f / dsum : 0.f;
    out[(size_t)blockIdx.x * KD + tid] = kn[(size_t)blockIdx.x * KD + tid] + s * rden;
  }
}

extern "C" void kernel_launch(void* const* d_in, const int* in_sizes, int n_in,
                              void* d_out, int out_size, void* d_ws, size_t ws_size,
                              hipStream_t stream){
  const int S  = in_sizes[0] / KD;     // 40000
  const int E  = in_sizes[1] / KD;     // 18000
  const int KN = in_sizes[2] / KD;     // 128
  const int nse = in_sizes[19];        // 1.5M
  const int nek = in_sizes[23];        // 180K

  const float* stu  = (const float*)d_in[0];
  const float* exer = (const float*)d_in[1];
  const float* kn   = (const float*)d_in[2];
  const float* sfe_fcW = (const float*)d_in[3];  const float* sfe_attn = (const float*)d_in[4];
  const float* efs_fcW = (const float*)d_in[5];  const float* efs_attn = (const float*)d_in[6];
  const float* efk_fcW = (const float*)d_in[7];  const float* efk_attn = (const float*)d_in[8];
  const float* kfe_fcW = (const float*)d_in[9];  const float* kfe_attn = (const float*)d_in[10];
  const float* ea0W = (const float*)d_in[13]; const float* ea0b = (const float*)d_in[14];
  const float* ea1W = (const float*)d_in[15]; const float* ea1b = (const float*)d_in[16];
  const int* sfe_src = (const int*)d_in[19]; const int* sfe_dst = (const int*)d_in[20];
  const int* efs_src = (const int*)d_in[21]; const int* efs_dst = (const int*)d_in[22];
  const int* efk_src = (const int*)d_in[23]; const int* efk_dst = (const int*)d_in[24];
  const int* kfe_src = (const int*)d_in[25]; const int* kfe_dst = (const int*)d_in[26];
  float* out = (float*)d_out;

  // ---- workspace carve-up ----
  char* w = (char*)d_ws;
  auto alloc = [&](size_t bytes) -> char* {
    char* p = w; w += (bytes + 255) & ~(size_t)255; return p;
  };
  short* Wb               = (short*)alloc((size_t)4 * 16384 * 2);
  __hip_bfloat16* z_sfe   = (__hip_bfloat16*)alloc((size_t)E  * KD * 2);
  __hip_bfloat16* z_efs   = (__hip_bfloat16*)alloc((size_t)S  * KD * 2);
  __hip_bfloat16* z_efk   = (__hip_bfloat16*)alloc((size_t)KN * KD * 2);
  __hip_bfloat16* z_kfe   = (__hip_bfloat16*)alloc((size_t)E  * KD * 2);
  float* ew_sfe = (float*)alloc((size_t)E  * 4);
  float* ew_efs = (float*)alloc((size_t)S  * 4);
  float* ew_efk = (float*)alloc((size_t)KN * 4);
  float* ew_kfe = (float*)alloc((size_t)E  * 4);
  const int NSEG = S + E + E + KN;     // 76128
  const size_t TOTE = 2 * (size_t)nse + 2 * (size_t)nek;
  const int NPLACE = (int)((TOTE + CHUNKP - 1) / CHUNKP);   // ~821
  int* pb256   = (int*)alloc((NBINS + 1) * 4);
  int* gcur    = (int*)alloc((size_t)NBINS * GSTR * 4);
  int* binbase = (int*)alloc(NBINS * 4);
  int* offs    = (int*)alloc((size_t)(NSEG + 1) * 4);
  u32* buckets = (u32*)alloc((size_t)NBINS * CAPB * 4);
  u16* edges   = (u16*)alloc(TOTE * 2);

  hipMemsetAsync(gcur, 0, (size_t)NBINS * GSTR * 4, stream);

  BinParams bp;
  bp.Cb[0] = 0; bp.Cb[1] = nse; bp.Cb[2] = 2L * nse; bp.Cb[3] = 2L * nse + nek;
  bp.base[0] = 0; bp.base[1] = S; bp.base[2] = S + E; bp.base[3] = S + 2 * E;
  bp.dr[0] = (double)nse / S; bp.dr[1] = (double)nse / E;
  bp.dr[2] = (double)nek / E; bp.dr[3] = (double)nek / KN;
  bp.dbin = (double)NBINS / (double)TOTE;
  bp.nseg = NSEG;

  k_pb256<<<1, 512, 0, stream>>>(bp, pb256);
  k_cvt_w<<<256, 256, 0, stream>>>(sfe_fcW, efs_fcW, efk_fcW, kfe_fcW, Wb);

  const int nbE = (E + 63) / 64, nbS = (S + 63) / 64, nbK = (KN + 63) / 64;
  MegaArgs ma;
  ma.d0 = sfe_dst; ma.s0 = sfe_src; ma.d1 = efs_dst; ma.s1 = efs_src;
  ma.d2 = efk_dst; ma.s2 = efk_src; ma.d3 = kfe_dst; ma.s3 = kfe_src;
  ma.nse = nse; ma.nek = nek; ma.rebase23 = S + E; ma.nplace = NPLACE;
  ma.buckets = buckets; ma.gcur = gcur; ma.pb = pb256; ma.bp = bp;
  ma.A0 = exer; ma.nA = E; ma.Wb = Wb;
  ma.j[0] = { stu, sfe_attn, z_sfe, ew_sfe, S, E,  0,               0 };
  ma.j[1] = { stu, efs_attn, z_efs, ew_efs, 0, S,  nbE,             16384 };
  ma.j[2] = { kn,  efk_attn, z_efk, ew_efk, E, KN, nbE + nbS,       32768 };
  ma.j[3] = { kn,  kfe_attn, z_kfe, ew_kfe, 0, E,  nbE + nbS + nbK, 49152 };
  k_megaF<<<NPLACE + nbE + nbS + nbK + nbE, 256, 0, stream>>>(ma);

  k_scan256<<<1, 256, 0, stream>>>(gcur, binbase);
  k_scatc<<<NBINS, 512, 0, stream>>>(buckets, gcur, binbase, pb256, offs, edges);

  k_aggK<<<KN, 512, 0, stream>>>(offs, S + 2 * E, edges, ew_kfe, z_kfe,
                                 kn, out + (size_t)(S + E) * KD);

  AggArgs aa;
  aa.offs = offs; aa.edges = edges;
  aa.ew_sfe = ew_sfe; aa.z_sfe = z_sfe;
  aa.ew_efs = ew_efs; aa.z_efs = z_efs;
  aa.ew_efk = ew_efk; aa.z_efk = z_efk;
  aa.stu = stu; aa.exer = exer; aa.out = out;
  aa.a0W = ea0W; aa.a0b = ea0b; aa.a1W = ea1W; aa.a1b = ea1b;
  aa.S = S; aa.E = E;
  k_aggW<<<(S + E + 3) / 4, 256, 0, stream>>>(aa);
}

// Round 22
// 214.671 us; speedup vs baseline: 1.1232x; 1.0683x over previous
//
#include <hip/hip_runtime.h>
#include <hip/hip_bf16.h>

using f32x4  = __attribute__((ext_vector_type(4))) float;
using bf16x8 = __attribute__((ext_vector_type(8))) short;
typedef unsigned int u32;
typedef unsigned short u16;

#define KD 128
#define NBINS 512
#define CHUNKP 4096     // place chunk (LDS-resident); 16 entries/thread
#define EPT 16
#define CAPB 8192
#define MAXB 10240
#define NSEGMAX 768
#define GSTR 16         // gcur padding stride (64B per bin)

__device__ inline float bf2f(short s){
  return __uint_as_float(((u32)(u16)s) << 16);
}

struct BinParams {
  long Cb[4]; int base[4]; double dr[4]; double dbin; int nseg;
};

__device__ inline int bin_of(int seg, const BinParams& bp){
  int r = (seg >= bp.base[1]) + (seg >= bp.base[2]) + (seg >= bp.base[3]);
  long ep = bp.Cb[r] + (long)((double)(seg - bp.base[r]) * bp.dr[r]);
  int b = (int)((double)ep * bp.dbin);
  return (b > NBINS - 1) ? (NBINS - 1) : b;
}

// ---------------- pb512: bin -> first seg ----------------
__global__ void k_pb512(BinParams bp, int* __restrict__ pb){
  int t = blockIdx.x * blockDim.x + threadIdx.x;
  if (t > NBINS) return;
  if (t == 0){ pb[0] = 0; return; }
  if (t == NBINS){ pb[NBINS] = bp.nseg; return; }
  int lo = 0, hi = bp.nseg;
  while (lo < hi){
    int mid = (lo + hi) >> 1;
    if (bin_of(mid, bp) >= t) hi = mid; else lo = mid + 1;
  }
  pb[t] = lo;
}

// ---------------- weight convert ----------------
__global__ __launch_bounds__(256) void k_cvt_w(const float* __restrict__ w0,
                                               const float* __restrict__ w1,
                                               const float* __restrict__ w2,
                                               const float* __restrict__ w3,
                                               short* __restrict__ out){
  int i = blockIdx.x * 256 + threadIdx.x;
  const float* src = (i < 16384) ? w0 : (i < 32768) ? w1 : (i < 49152) ? w2 : w3;
  float v = src[i & 16383];
  __hip_bfloat16 b = __float2bfloat16(v);
  out[i] = __builtin_bit_cast(short, b);
}

// ---------------- shared-memory overlay structs (256-thread fused kernel) ----------------
struct PlaceSh {
  u32 sorted[CHUNKP];
  u16 sbid[CHUNKP];
  int cnt[NBINS];
  int lbase[NBINS];
  int lpos[NBINS];
  int pbL[NBINS];
  int sc[256];
};
struct GemmSh { short zst[4][16][136]; };

// ---------------- GEMM z = h @ W^T (+ ews = exp(z . attn)) ----------------
struct GJob { const float* A1; const float* attn; __hip_bfloat16* Z; float* ews;
              int zbase, nrows, blk0, wboff; };

__device__ void gemm_body(GemmSh* g,
                          const float* __restrict__ A0, int nA,
                          const float* __restrict__ A1,
                          const short* __restrict__ Wb, const float* __restrict__ attn,
                          __hip_bfloat16* __restrict__ Z, float* __restrict__ ews,
                          int zbase, int nrows, int blk)
{
  const int wave = threadIdx.x >> 6, lane = threadIdx.x & 63;
  const int lr = lane & 15, lk = lane >> 4;
  const int row0 = blk * 64 + wave * 16;

  bf16x8 afrag[4];
  {
    int r = row0 + lr;
    bool rv = (r < nrows);
    int node = zbase + r;
    const float* ap = A0;
    if (rv) ap = (node < nA) ? (A0 + (size_t)node * KD) : (A1 + (size_t)(node - nA) * KD);
#pragma unroll
    for (int t = 0; t < 4; ++t){
      float x[8];
      if (rv){
        float4 u0 = *(const float4*)(ap + t * 32 + lk * 8);
        float4 u1 = *(const float4*)(ap + t * 32 + lk * 8 + 4);
        x[0]=u0.x; x[1]=u0.y; x[2]=u0.z; x[3]=u0.w;
        x[4]=u1.x; x[5]=u1.y; x[6]=u1.z; x[7]=u1.w;
      } else {
#pragma unroll
        for (int j = 0; j < 8; ++j) x[j] = 0.f;
      }
      bf16x8 af;
#pragma unroll
      for (int j = 0; j < 8; ++j){
        __hip_bfloat16 b = __float2bfloat16(x[j]);
        af[j] = __builtin_bit_cast(short, b);
      }
      afrag[t] = af;
    }
  }

  f32x4 acc[8];
#pragma unroll
  for (int c = 0; c < 8; ++c){ acc[c][0]=0.f; acc[c][1]=0.f; acc[c][2]=0.f; acc[c][3]=0.f; }

#pragma unroll
  for (int c = 0; c < 8; ++c){
#pragma unroll
    for (int t = 0; t < 4; ++t){
      bf16x8 bf = *(const bf16x8*)(Wb + (c * 16 + lr) * KD + t * 32 + lk * 8);
      acc[c] = __builtin_amdgcn_mfma_f32_16x16x32_bf16(afrag[t], bf, acc[c], 0, 0, 0);
    }
  }

  float p[4] = {0.f, 0.f, 0.f, 0.f};
#pragma unroll
  for (int c = 0; c < 8; ++c){
    float av = attn[c * 16 + lr];
#pragma unroll
    for (int q = 0; q < 4; ++q){
      p[q] += acc[c][q] * av;
      g->zst[wave][lk * 4 + q][c * 16 + lr] =
          __builtin_bit_cast(short, __float2bfloat16(acc[c][q]));
    }
  }
#pragma unroll
  for (int q = 0; q < 4; ++q){
#pragma unroll
    for (int o = 1; o < 16; o <<= 1) p[q] += __shfl_xor(p[q], o, 64);
  }
  if (lr == 0){
#pragma unroll
    for (int q = 0; q < 4; ++q){
      int r = row0 + lk * 4 + q;
      if (r < nrows) ews[r] = __expf(p[q]);   // max-shift cancels in segment softmax
    }
  }
  __syncthreads();
#pragma unroll
  for (int pq = 0; pq < 4; ++pq){
    int row = pq * 4 + (lane >> 4);
    int col8 = (lane & 15) * 8;
    bf16x8 v = *(const bf16x8*)&g->zst[wave][row][col8];
    int r = row0 + row;
    if (r < nrows) *(bf16x8*)(Z + (size_t)r * KD + col8) = v;
  }
}

// ---------------- megaF: place blocks + gemm blocks (256 threads, LDS overlay) ----------------
struct MegaArgs {
  const int* d0; const int* s0; const int* d1; const int* s1;
  const int* d2; const int* s2; const int* d3; const int* s3;
  int nse, nek, rebase23, nplace;
  u32* buckets;
  int* gcur;              // padded: bin j at gcur[j*GSTR]
  const int* pb;
  BinParams bp;
  const float* A0; int nA;
  const short* Wb;
  GJob j[4];
};

__global__ __launch_bounds__(256) void k_megaF(MegaArgs a){
  __shared__ alignas(16) char shraw[sizeof(PlaceSh)];
  const int tid = threadIdx.x;
  const int b = blockIdx.x;
  if (b < a.nplace){
    PlaceSh& P = *reinterpret_cast<PlaceSh*>(shraw);
    for (int j = tid; j < NBINS; j += 256){ P.cnt[j] = 0; P.pbL[j] = a.pb[j]; }
    __syncthreads();
    const long total = 2L * a.nse + 2L * a.nek;
    long c0 = (long)b * CHUNKP;
    long c1 = c0 + CHUNKP; if (c1 > total) c1 = total;

    // pass A: load once, stage entries in registers, build local hist
    u32 re[EPT];
    int rbn[EPT];
#pragma unroll
    for (int it = 0; it < EPT; ++it){
      long i = c0 + (long)it * 256 + tid;
      rbn[it] = -1;
      if (i < c1){
        long k = i; const int* dp; const int* sp; int rb;
        if (k < a.nse){ dp = a.d0; sp = a.s0; rb = 0; }
        else if ((k -= a.nse) < a.nse){ dp = a.d1; sp = a.s1; rb = 0; }
        else if ((k -= a.nse) < a.nek){ dp = a.d2; sp = a.s2; rb = a.rebase23; }
        else { k -= a.nek; dp = a.d3; sp = a.s3; rb = a.rebase23; }
        int seg = dp[k] + rb;
        int bn = bin_of(seg, a.bp);
        re[it]  = ((u32)(seg - P.pbL[bn]) << 16) | (u32)sp[k];
        rbn[it] = bn;
        atomicAdd(&P.cnt[bn], 1);
      }
    }
    __syncthreads();
    // exclusive scan (512 bins, 256 threads, 2 rounds)
    int carry = 0;
    for (int cb = 0; cb < NBINS; cb += 256){
      int j = cb + tid;
      int v = P.cnt[j];
      P.sc[tid] = v; __syncthreads();
      for (int o = 1; o < 256; o <<= 1){
        int u = (tid >= o) ? P.sc[tid - o] : 0;
        __syncthreads();
        P.sc[tid] += u;
        __syncthreads();
      }
      P.lbase[j] = carry + P.sc[tid] - v;
      P.lpos[j]  = P.lbase[j];
      carry += P.sc[255];
      __syncthreads();
    }
    // reserve global runs (padded gcur); cnt[] becomes gbs[]
    for (int j = tid; j < NBINS; j += 256){
      int c = P.cnt[j];
      P.cnt[j] = c ? atomicAdd(&a.gcur[j * GSTR], c) : 0;
    }
    __syncthreads();
    // pass B: scatter from registers into LDS (sorted by bin)
#pragma unroll
    for (int it = 0; it < EPT; ++it){
      if (rbn[it] >= 0){
        int p = atomicAdd(&P.lpos[rbn[it]], 1);
        P.sorted[p] = re[it];
        P.sbid[p] = (u16)rbn[it];
      }
    }
    __syncthreads();
    // coalesced-run dump into per-bin buckets
    int n = (int)(c1 - c0);
    for (int i = tid; i < n; i += 256){
      int bn = P.sbid[i];
      int idx = P.cnt[bn] + (i - P.lbase[bn]);
      if (idx < CAPB)
        __builtin_nontemporal_store(P.sorted[i], &a.buckets[(size_t)bn * CAPB + idx]);
    }
  } else {
    GemmSh* G = reinterpret_cast<GemmSh*>(shraw);
    int gb = b - a.nplace;
    int ji = 3;
    if (gb < a.j[1].blk0) ji = 0;
    else if (gb < a.j[2].blk0) ji = 1;
    else if (gb < a.j[3].blk0) ji = 2;
    GJob J = a.j[ji];
    gemm_body(G, a.A0, a.nA, J.A1, a.Wb + J.wboff, J.attn, J.Z, J.ews,
              J.zbase, J.nrows, gb - J.blk0);
  }
}

// ---------------- scan of 512 bin counts -> bin bases ----------------
__global__ __launch_bounds__(512) void k_scan512(const int* __restrict__ gcur,
                                                 int* __restrict__ binbase){
  __shared__ int sh[512];
  int tid = threadIdx.x;
  int v = gcur[tid * GSTR];
  sh[tid] = v; __syncthreads();
  for (int o = 1; o < 512; o <<= 1){
    int u = (tid >= o) ? sh[tid - o] : 0;
    __syncthreads();
    sh[tid] += u;
    __syncthreads();
  }
  binbase[tid] = sh[tid] - v;   // exclusive
}

// ---------------- scatc: per-bin LDS CSR sort, coalesced u16 dump ----------------
__global__ __launch_bounds__(512) void k_scatc(const u32* __restrict__ buckets,
                                               const int* __restrict__ gcur,
                                               const int* __restrict__ binbase,
                                               const int* __restrict__ pb,
                                               int* __restrict__ offs,
                                               u16* __restrict__ edges){
  __shared__ u16 els[MAXB];
  __shared__ int pc[NSEGMAX + 1];
  __shared__ int sc[512];
  const int t = blockIdx.x;
  const int tid = threadIdx.x;
  const int base = binbase[t];
  int n = gcur[t * GSTR]; if (n > CAPB) n = CAPB;
  const int lo = pb[t], hi = pb[t + 1];
  const int nsl = hi - lo;

  for (int j = tid; j < nsl; j += 512) pc[j] = 0;
  __syncthreads();
  for (int i = tid; i < n; i += 512){
    u32 e = buckets[(size_t)t * CAPB + i];
    int srel = (int)(e >> 16);
    if (srel < nsl) atomicAdd(&pc[srel], 1);
  }
  __syncthreads();
  int carry = 0;
  for (int cb = 0; cb < nsl; cb += 512){
    int j = cb + tid;
    int v = (j < nsl) ? pc[j] : 0;
    sc[tid] = v; __syncthreads();
    for (int o = 1; o < 512; o <<= 1){
      int u = (tid >= o) ? sc[tid - o] : 0;
      __syncthreads();
      sc[tid] += u;
      __syncthreads();
    }
    if (j < nsl) pc[j] = carry + sc[tid] - v;
    carry += sc[511];
    __syncthreads();
  }
  for (int j = tid; j < nsl; j += 512) offs[lo + j] = base + pc[j];
  if (t == NBINS - 1 && tid == 0) offs[hi] = base + n;
  __syncthreads();

  for (int i = tid; i < n; i += 512){
    u32 e = buckets[(size_t)t * CAPB + i];
    int srel = (int)(e >> 16);
    if (srel < nsl){
      int pos = atomicAdd(&pc[srel], 1);
      els[pos] = (u16)(e & 0xffffu);
    }
  }
  __syncthreads();
  int st = base & 1;
  if (st && tid == 0) edges[base] = els[0];
  int m = n - st;
  int nh = m >> 1;
  u32* dst = (u32*)(edges + base + st);
  for (int i2 = tid; i2 < nh; i2 += 512){
    u32 v = ((u32)els[st + 2 * i2 + 1] << 16) | (u32)els[st + 2 * i2];
    __builtin_nontemporal_store(v, &dst[i2]);
  }
  if ((m & 1) && tid == 0) edges[base + n - 1] = els[n - 1];
}

// ---------------- wave-per-segment aggregation (students + exercises) ----------------
// 4-deep unrolled gather: four edge rows in flight per slot for MLP.
#define GATHER4(EW, Z, ZB, ACC, DS, BEG, END)                                   \
  {                                                                             \
    int i = (BEG) + slot;                                                       \
    for (; i + 12 < (END); i += 16){                                            \
      int r0 = (int)a.edges[i]      - (ZB);                                     \
      int r1 = (int)a.edges[i + 4]  - (ZB);                                     \
      int r2 = (int)a.edges[i + 8]  - (ZB);                                     \
      int r3 = (int)a.edges[i + 12] - (ZB);                                     \
      float w0 = (EW)[r0], w1 = (EW)[r1], w2 = (EW)[r2], w3 = (EW)[r3];         \
      bf16x8 z0 = *(const bf16x8*)((Z) + (size_t)r0 * KD + li * 8);             \
      bf16x8 z1 = *(const bf16x8*)((Z) + (size_t)r1 * KD + li * 8);             \
      bf16x8 z2 = *(const bf16x8*)((Z) + (size_t)r2 * KD + li * 8);             \
      bf16x8 z3 = *(const bf16x8*)((Z) + (size_t)r3 * KD + li * 8);             \
      (DS) += (w0 + w1) + (w2 + w3);                                            \
      _Pragma("unroll")                                                         \
      for (int j = 0; j < 8; ++j){                                              \
        (ACC)[j] = fmaf(w0, bf2f(z0[j]), (ACC)[j]);                             \
        (ACC)[j] = fmaf(w1, bf2f(z1[j]), (ACC)[j]);                             \
        (ACC)[j] = fmaf(w2, bf2f(z2[j]), (ACC)[j]);                             \
        (ACC)[j] = fmaf(w3, bf2f(z3[j]), (ACC)[j]);                             \
      }                                                                         \
    }                                                                           \
    for (; i < (END); i += 4){                                                  \
      int r0 = (int)a.edges[i] - (ZB);                                          \
      float w0 = (EW)[r0];                                                      \
      bf16x8 z0 = *(const bf16x8*)((Z) + (size_t)r0 * KD + li * 8);             \
      (DS) += w0;                                                               \
      _Pragma("unroll")                                                         \
      for (int j = 0; j < 8; ++j) (ACC)[j] = fmaf(w0, bf2f(z0[j]), (ACC)[j]);   \
    }                                                                           \
  }

struct AggArgs {
  const int* offs; const u16* edges;
  const float* ew_sfe; const __hip_bfloat16* z_sfe;
  const float* ew_efs; const __hip_bfloat16* z_efs;
  const float* ew_efk; const __hip_bfloat16* z_efk;
  const float* stu; const float* exer;
  float* out;
  const float* a0W; const float* a0b; const float* a1W; const float* a1b;
  int S, E;
};

__global__ __launch_bounds__(256) void k_aggW(AggArgs a){
  const int lane = threadIdx.x & 63;
  const int wave = threadIdx.x >> 6;
  const int li = lane & 15;
  const int slot = lane >> 4;
  const int gs = blockIdx.x * 4 + wave;
  if (gs >= a.S + a.E) return;

  if (gs < a.S){
    const int beg = a.offs[gs], end = a.offs[gs + 1];
    float acc[8];
#pragma unroll
    for (int j = 0; j < 8; ++j) acc[j] = 0.f;
    float ds = 0.f;
    GATHER4(a.ew_sfe, a.z_sfe, a.S, acc, ds, beg, end)
#pragma unroll
    for (int j = 0; j < 8; ++j){
      acc[j] += __shfl_xor(acc[j], 16, 64);
      acc[j] += __shfl_xor(acc[j], 32, 64);
    }
    ds += __shfl_xor(ds, 16, 64);
    ds += __shfl_xor(ds, 32, 64);
    float rden = (end > beg) ? 1.f / ds : 0.f;
    if (lane < 32){
      const size_t o = (size_t)gs * KD + li * 8 + slot * 4;
      const float* emb = a.stu + o;
      float4 v;
      v.x = emb[0] + acc[slot * 4 + 0] * rden;
      v.y = emb[1] + acc[slot * 4 + 1] * rden;
      v.z = emb[2] + acc[slot * 4 + 2] * rden;
      v.w = emb[3] + acc[slot * 4 + 3] * rden;
      *(float4*)(a.out + o) = v;
    }
  } else {
    const int e = gs - a.S;
    const int b1 = a.offs[a.S + e], e1 = a.offs[a.S + e + 1];
    const int b2 = a.offs[a.S + a.E + e], e2 = a.offs[a.S + a.E + e + 1];
    float acc1[8], acc2[8];
#pragma unroll
    for (int j = 0; j < 8; ++j){ acc1[j] = 0.f; acc2[j] = 0.f; }
    float ds1 = 0.f, ds2 = 0.f;
    GATHER4(a.ew_efs, a.z_efs, 0,   acc1, ds1, b1, e1)
    GATHER4(a.ew_efk, a.z_efk, a.E, acc2, ds2, b2, e2)
#pragma unroll
    for (int j = 0; j < 8; ++j){
      acc1[j] += __shfl_xor(acc1[j], 16, 64);
      acc1[j] += __shfl_xor(acc1[j], 32, 64);
      acc2[j] += __shfl_xor(acc2[j], 16, 64);
      acc2[j] += __shfl_xor(acc2[j], 32, 64);
    }
    ds1 += __shfl_xor(ds1, 16, 64); ds1 += __shfl_xor(ds1, 32, 64);
    ds2 += __shfl_xor(ds2, 16, 64); ds2 += __shfl_xor(ds2, 32, 64);
    float r1 = (e1 > b1) ? 1.f / ds1 : 0.f;
    float r2 = (e2 > b2) ? 1.f / ds2 : 0.f;
    float aw1[8], aw2[8];
#pragma unroll
    for (int j = 0; j < 8; ++j){ aw1[j] = acc1[j] * r1; aw2[j] = acc2[j] * r2; }

    float ex8[8];
    {
      float4 u0 = *(const float4*)(a.exer + (size_t)e * KD + li * 8);
      float4 u1 = *(const float4*)(a.exer + (size_t)e * KD + li * 8 + 4);
      ex8[0]=u0.x; ex8[1]=u0.y; ex8[2]=u0.z; ex8[3]=u0.w;
      ex8[4]=u1.x; ex8[5]=u1.y; ex8[6]=u1.z; ex8[7]=u1.w;
    }
    float q0 = 0.f, q1 = 0.f;
#pragma unroll
    for (int j = 0; j < 8; ++j){
      q0 += ex8[j] * a.a0W[li * 8 + j] + aw1[j] * a.a0W[KD + li * 8 + j];
      q1 += ex8[j] * a.a1W[li * 8 + j] + aw2[j] * a.a1W[KD + li * 8 + j];
    }
#pragma unroll
    for (int o = 1; o < 16; o <<= 1){
      q0 += __shfl_xor(q0, o, 64);
      q1 += __shfl_xor(q1, o, 64);
    }
    float sc0 = q0 + a.a0b[0], sc1 = q1 + a.a1b[0];
    float mx = fmaxf(sc0, sc1);
    float w0 = __expf(sc0 - mx), w1 = __expf(sc1 - mx);
    float inv = 1.f / (w0 + w1);
    w0 *= inv; w1 *= inv;
    if (lane < 32){
      const size_t o = (size_t)gs * KD + li * 8 + slot * 4;
      float4 v;
#pragma unroll
      for (int q = 0; q < 4; ++q){
        int j = slot * 4 + q;
        ((float*)&v)[q] = ex8[j] + w0 * aw1[j] + w1 * aw2[j];
      }
      *(float4*)(a.out + o) = v;
    }
  }
}

// ---------------- knowledge aggregation: block-per-seg, 4-deep ----------------
__global__ __launch_bounds__(512) void k_aggK(const int* __restrict__ offs, int segbase,
                                              const u16* __restrict__ edges,
                                              const float* __restrict__ ews,
                                              const __hip_bfloat16* __restrict__ Z,
                                              const float* __restrict__ kn,
                                              float* __restrict__ out){
  __shared__ float sred[8];
  __shared__ float lacc[8][KD];
  const int tid = threadIdx.x;
  const int wave = tid >> 6, lane = tid & 63;
  const int sub = lane >> 4, li = lane & 15;
  const int seg = segbase + blockIdx.x;
  const int beg = offs[seg], end = offs[seg + 1];

  float acc[8];
#pragma unroll
  for (int j = 0; j < 8; ++j) acc[j] = 0.f;
  float ds = 0.f;
  const int slot = wave * 4 + sub;
  {
    int i = beg + slot;
    for (; i + 96 < end; i += 128){
      int r0 = (int)edges[i];
      int r1 = (int)edges[i + 32];
      int r2 = (int)edges[i + 64];
      int r3 = (int)edges[i + 96];
      float w0 = ews[r0], w1 = ews[r1], w2 = ews[r2], w3 = ews[r3];
      bf16x8 z0 = *(const bf16x8*)(Z + (size_t)r0 * KD + li * 8);
      bf16x8 z1 = *(const bf16x8*)(Z + (size_t)r1 * KD + li * 8);
      bf16x8 z2 = *(const bf16x8*)(Z + (size_t)r2 * KD + li * 8);
      bf16x8 z3 = *(const bf16x8*)(Z + (size_t)r3 * KD + li * 8);
      ds += (w0 + w1) + (w2 + w3);
#pragma unroll
      for (int j = 0; j < 8; ++j){
        acc[j] = fmaf(w0, bf2f(z0[j]), acc[j]);
        acc[j] = fmaf(w1, bf2f(z1[j]), acc[j]);
        acc[j] = fmaf(w2, bf2f(z2[j]), acc[j]);
        acc[j] = fmaf(w3, bf2f(z3[j]), acc[j]);
      }
    }
    for (; i < end; i += 32){
      int r0 = (int)edges[i];
      float w0 = ews[r0];
      bf16x8 z0 = *(const bf16x8*)(Z + (size_t)r0 * KD + li * 8);
      ds += w0;
#pragma unroll
      for (int j = 0; j < 8; ++j) acc[j] = fmaf(w0, bf2f(z0[j]), acc[j]);
    }
  }
#pragma unroll
  for (int j = 0; j < 8; ++j){
    acc[j] += __shfl_xor(acc[j], 16, 64);
    acc[j] += __shfl_xor(acc[j], 32, 64);
  }
  ds += __shfl_xor(ds, 16, 64);
  ds += __shfl_xor(ds, 32, 64);
  if (lane == 0) sred[wave] = ds;
  if (sub == 0){
    f32x4 v0, v1;
#pragma unroll
    for (int j = 0; j < 4; ++j){ v0[j] = acc[j]; v1[j] = acc[4 + j]; }
    *(f32x4*)&lacc[wave][li * 8]     = v0;
    *(f32x4*)&lacc[wave][li * 8 + 4] = v1;
  }
  __syncthreads();
  if (tid < KD){
    float dsum = 0.f;
#pragma unroll
    for (int wv = 0; wv < 8; ++wv) dsum += sred[wv];
    float s = 0.f;
#pragma unroll
    for (int wv = 0; wv < 8; ++wv) s += lacc[wv][tid];
    float rden = (end > beg) ? 1.f / dsum : 0.f;
    out[(size_t)blockIdx.x * KD + tid] = kn[(size_t)blockIdx.x * KD + tid] + s * rden;
  }
}

extern "C" void kernel_launch(void* const* d_in, const int* in_sizes, int n_in,
                              void* d_out, int out_size, void* d_ws, size_t ws_size,
                              hipStream_t stream){
  const int S  = in_sizes[0] / KD;     // 40000
  const int E  = in_sizes[1] / KD;     // 18000
  const int KN = in_sizes[2] / KD;     // 128
  const int nse = in_sizes[19];        // 1.5M
  const int nek = in_sizes[23];        // 180K

  const float* stu  = (const float*)d_in[0];
  const float* exer = (const float*)d_in[1];
  const float* kn   = (const float*)d_in[2];
  const float* sfe_fcW = (const float*)d_in[3];  const float* sfe_attn = (const float*)d_in[4];
  const float* efs_fcW = (const float*)d_in[5];  const float* efs_attn = (const float*)d_in[6];
  const float* efk_fcW = (const float*)d_in[7];  const float* efk_attn = (const float*)d_in[8];
  const float* kfe_fcW = (const float*)d_in[9];  const float* kfe_attn = (const float*)d_in[10];
  const float* ea0W = (const float*)d_in[13]; const float* ea0b = (const float*)d_in[14];
  const float* ea1W = (const float*)d_in[15]; const float* ea1b = (const float*)d_in[16];
  const int* sfe_src = (const int*)d_in[19]; const int* sfe_dst = (const int*)d_in[20];
  const int* efs_src = (const int*)d_in[21]; const int* efs_dst = (const int*)d_in[22];
  const int* efk_src = (const int*)d_in[23]; const int* efk_dst = (const int*)d_in[24];
  const int* kfe_src = (const int*)d_in[25]; const int* kfe_dst = (const int*)d_in[26];
  float* out = (float*)d_out;

  // ---- workspace carve-up ----
  char* w = (char*)d_ws;
  auto alloc = [&](size_t bytes) -> char* {
    char* p = w; w += (bytes + 255) & ~(size_t)255; return p;
  };
  short* Wb               = (short*)alloc((size_t)4 * 16384 * 2);
  __hip_bfloat16* z_sfe   = (__hip_bfloat16*)alloc((size_t)E  * KD * 2);
  __hip_bfloat16* z_efs   = (__hip_bfloat16*)alloc((size_t)S  * KD * 2);
  __hip_bfloat16* z_efk   = (__hip_bfloat16*)alloc((size_t)KN * KD * 2);
  __hip_bfloat16* z_kfe   = (__hip_bfloat16*)alloc((size_t)E  * KD * 2);
  float* ew_sfe = (float*)alloc((size_t)E  * 4);
  float* ew_efs = (float*)alloc((size_t)S  * 4);
  float* ew_efk = (float*)alloc((size_t)KN * 4);
  float* ew_kfe = (float*)alloc((size_t)E  * 4);
  const int NSEG = S + E + E + KN;     // 76128
  const size_t TOTE = 2 * (size_t)nse + 2 * (size_t)nek;
  const int NPLACE = (int)((TOTE + CHUNKP - 1) / CHUNKP);   // ~821
  int* pb512   = (int*)alloc((NBINS + 1) * 4);
  int* gcur    = (int*)alloc((size_t)NBINS * GSTR * 4);
  int* binbase = (int*)alloc(NBINS * 4);
  int* offs    = (int*)alloc((size_t)(NSEG + 1) * 4);
  u32* buckets = (u32*)alloc((size_t)NBINS * CAPB * 4);
  u16* edges   = (u16*)alloc(TOTE * 2);

  hipMemsetAsync(gcur, 0, (size_t)NBINS * GSTR * 4, stream);

  BinParams bp;
  bp.Cb[0] = 0; bp.Cb[1] = nse; bp.Cb[2] = 2L * nse; bp.Cb[3] = 2L * nse + nek;
  bp.base[0] = 0; bp.base[1] = S; bp.base[2] = S + E; bp.base[3] = S + 2 * E;
  bp.dr[0] = (double)nse / S; bp.dr[1] = (double)nse / E;
  bp.dr[2] = (double)nek / E; bp.dr[3] = (double)nek / KN;
  bp.dbin = (double)NBINS / (double)TOTE;
  bp.nseg = NSEG;

  k_pb512<<<1, 1024, 0, stream>>>(bp, pb512);
  k_cvt_w<<<256, 256, 0, stream>>>(sfe_fcW, efs_fcW, efk_fcW, kfe_fcW, Wb);

  const int nbE = (E + 63) / 64, nbS = (S + 63) / 64, nbK = (KN + 63) / 64;
  MegaArgs ma;
  ma.d0 = sfe_dst; ma.s0 = sfe_src; ma.d1 = efs_dst; ma.s1 = efs_src;
  ma.d2 = efk_dst; ma.s2 = efk_src; ma.d3 = kfe_dst; ma.s3 = kfe_src;
  ma.nse = nse; ma.nek = nek; ma.rebase23 = S + E; ma.nplace = NPLACE;
  ma.buckets = buckets; ma.gcur = gcur; ma.pb = pb512; ma.bp = bp;
  ma.A0 = exer; ma.nA = E; ma.Wb = Wb;
  ma.j[0] = { stu, sfe_attn, z_sfe, ew_sfe, S, E,  0,               0 };
  ma.j[1] = { stu, efs_attn, z_efs, ew_efs, 0, S,  nbE,             16384 };
  ma.j[2] = { kn,  efk_attn, z_efk, ew_efk, E, KN, nbE + nbS,       32768 };
  ma.j[3] = { kn,  kfe_attn, z_kfe, ew_kfe, 0, E,  nbE + nbS + nbK, 49152 };
  k_megaF<<<NPLACE + nbE + nbS + nbK + nbE, 256, 0, stream>>>(ma);

  k_scan512<<<1, 512, 0, stream>>>(gcur, binbase);
  k_scatc<<<NBINS, 512, 0, stream>>>(buckets, gcur, binbase, pb512, offs, edges);

  k_aggK<<<KN, 512, 0, stream>>>(offs, S + 2 * E, edges, ew_kfe, z_kfe,
                                 kn, out + (size_t)(S + E) * KD);

  AggArgs aa;
  aa.offs = offs; aa.edges = edges;
  aa.ew_sfe = ew_sfe; aa.z_sfe = z_sfe;
  aa.ew_efs = ew_efs; aa.z_efs = z_efs;
  aa.ew_efk = ew_efk; aa.z_efk = z_efk;
  aa.stu = stu; aa.exer = exer; aa.out = out;
  aa.a0W = ea0W; aa.a0b = ea0b; aa.a1W = ea1W; aa.a1b = ea1b;
  aa.S = S; aa.E = E;
  k_aggW<<<(S + E + 3) / 4, 256, 0, stream>>>(aa);
}